// Round 1
// baseline (174.040 us; speedup 1.0000x reference)
//
#include <hip/hip_runtime.h>

// N=524288, D=9, E=2, H=128, M=32, O=2, K=1.
// LAYOUT (confirmed R6): d_in fp32, d_out FP32 (N*2 outputs + 1 loss).
// NUMERICS: pure fp32 everywhere, no rounding anywhere (see prior session).
// This round: block-local stable partition by expert -> expert-uniform waves
// run a single-expert loop (12 VALU/j, 12 s_load dwords/j) with arithmetic
// bit-identical to the accepted dense kernel's selected-expert chain.
// finalize folded into moe_main via done-counter (2 kernels total).
#define NTOK 524288
#define TPB  256
#define NBLK (NTOK / TPB)   // 2048

__device__ __forceinline__ float bf2f(unsigned short u) {
    union { unsigned int i; float f; } v;
    v.i = ((unsigned int)u) << 16;
    return v.f;
}

// input load: raw fp32 (bf16-buffer fallback kept purely as safety)
__device__ __forceinline__ float ldq(const void* p, int i, bool f32) {
    if (f32) return ((const float*)p)[i];
    return bf2f(((const unsigned short*)p)[i]);
}

// ---------------------------------------------------------------------------
// Prep: detect buffer dtype (safety), zero counters, stage w_gate, fold
// W2@Wout (+ b2@Wout + bout), pack per-hidden-unit weights.
// NEW wpack layout (expert-major, for uniform-wave scalar streams):
//   wpack[e*1536 + j*12 + {0..8:W1col, 9:b1, 10..11:W2'}]  (48B records, 16B-aligned)
// ---------------------------------------------------------------------------
__global__ void prep_kernel(const void* __restrict__ num_prop,
                            const void* __restrict__ wgate,
                            const void* __restrict__ W1,
                            const void* __restrict__ b1,
                            const void* __restrict__ W2,
                            const void* __restrict__ b2,
                            const void* __restrict__ Wout,
                            const void* __restrict__ bout,
                            unsigned int* __restrict__ cnt_done,  // [cnt1, done]
                            int* __restrict__ flag,
                            float* __restrict__ bpp,
                            float* __restrict__ wgf,
                            float* __restrict__ wpack)
{
    __shared__ int sflag;
    const int t = threadIdx.x;
    if (t == 0) {
        const unsigned short* u = (const unsigned short*)num_prop;
        int f = 0;
        for (int i = 0; i < 72; ++i) {
            int e = (u[i] >> 7) & 0xFF;
            if (e < 64 || e > 191) f = 1;
        }
        sflag = f; *flag = f; cnt_done[0] = 0u; cnt_done[1] = 0u;
    }
    __syncthreads();
    const bool f32 = (sflag != 0);

    if (t < 18) wgf[t] = ldq(wgate, t, f32);        // w_gate [9,2] raw fp32

    if (t < 4) {  // b''[e][o] = sum_m b2[e][m]*Wout[m][o] + bout[o]
        int e = t >> 1, o = t & 1;
        float acc = ldq(bout, o, f32);
        for (int m = 0; m < 32; ++m)
            acc += ldq(b2, e * 32 + m, f32) * ldq(Wout, m * 2 + o, f32);
        bpp[t] = acc;
    }

    const int e = t >> 7;       // 256 threads -> (e, j)
    const int j = t & 127;
    float p0 = 0.f, p1 = 0.f;
    for (int m = 0; m < 32; ++m) {
        float w = ldq(W2, (e * 128 + j) * 32 + m, f32);
        p0 += w * ldq(Wout, m * 2 + 0, f32);
        p1 += w * ldq(Wout, m * 2 + 1, f32);
    }
    float* dst = wpack + e * 1536 + j * 12;
    #pragma unroll
    for (int d = 0; d < 9; ++d)
        dst[d] = ldq(W1, (e * 9 + d) * 128 + j, f32);
    dst[9]  = ldq(b1, e * 128 + j, f32);
    dst[10] = p0;
    dst[11] = p1;
}

// ---------------------------------------------------------------------------
// Main: stage x -> LDS, gate, block-local stable partition by expert via
// ballot+prefix (smap: slot -> token). Waves whose 64-slot range avoids the
// n0 boundary are expert-uniform -> single-expert loop, scalar weights
// (readfirstlane makes n0/wbase provably SGPR -> s_load + s_cbranch).
// Boundary wave (<=1 per block) runs the dense-both body + select.
// Results bounce through LDS back to token order -> coalesced float2 stores.
// Last block to finish computes the loss (threadfence + done counter).
// ---------------------------------------------------------------------------
__global__ __launch_bounds__(TPB, 8)
void moe_main(const void* __restrict__ xg,
              const int* __restrict__ flag,
              const float* __restrict__ wgf,
              const float* __restrict__ bpp,
              const float* __restrict__ wpack,
              unsigned int* __restrict__ cnt_done,   // [cnt1, done]
              float2* __restrict__ out,
              float* __restrict__ loss_out)
{
    __shared__ float xs[TPB * 9];
    __shared__ unsigned char smap[TPB];
    __shared__ unsigned int wcnt[4];

    const int tid  = threadIdx.x;
    const int lane = tid & 63;
    const int wave = tid >> 6;

    const bool f32 = (*flag) != 0;
    const int gbase = blockIdx.x * (TPB * 9);
    if (f32) {
        const float* xf = (const float*)xg;
        #pragma unroll
        for (int i = 0; i < 9; ++i)
            xs[tid + i * TPB] = xf[gbase + tid + i * TPB];   // RAW fp32
    } else {
        const unsigned short* xu = (const unsigned short*)xg;
        for (int i = tid; i < TPB * 9; i += TPB)
            xs[i] = bf2f(xu[gbase + i]);
    }
    __syncthreads();

    // --- gate for own token ---
    float l0 = 0.f, l1 = 0.f;
    #pragma unroll
    for (int d = 0; d < 9; ++d) {
        float xv = xs[tid * 9 + d];
        l0 = fmaf(xv, wgf[d * 2 + 0], l0);
        l1 = fmaf(xv, wgf[d * 2 + 1], l1);
    }
    const bool e1 = l1 > l0;   // tie -> expert 0 (stable top_k)

    // --- stable partition: expert-0 tokens to slots [0,n0), expert-1 after ---
    unsigned long long bal = __ballot(e1);
    if (lane == 0) wcnt[wave] = (unsigned int)__popcll(bal);
    __syncthreads();
    int pre = 0, tot = 0;
    #pragma unroll
    for (int w = 0; w < 4; ++w) {
        int c = (int)wcnt[w];
        if (w < wave) pre += c;
        tot += c;
    }
    const int n1 = tot;
    const int n0 = TPB - n1;
    const int p1 = pre + (int)__popcll(bal & ((1ull << lane) - 1ull));
    const int slot = e1 ? (n0 + p1) : (tid - p1);
    smap[slot] = (unsigned char)tid;
    if (tid == 0) atomicAdd(&cnt_done[0], (unsigned int)n1);
    __syncthreads();

    // --- this thread now processes slot `tid` ---
    const int t = (int)smap[tid];
    float x[9];
    #pragma unroll
    for (int d = 0; d < 9; ++d) x[d] = xs[t * 9 + d];

    // scalarize the uniformity test so the fast path keeps s_load weights
    const int wbase = __builtin_amdgcn_readfirstlane(tid) & 192;  // wave*64
    const int n0u   = __builtin_amdgcn_readfirstlane(n0);

    float2 res;
    if (n0u <= wbase || n0u >= wbase + 64) {
        // expert-uniform wave: single-expert loop, 12 VALU/j, 12 s_load dwords/j
        const int ew = (n0u <= wbase) ? 1 : 0;
        const float* wp = wpack + ew * 1536;
        float a0 = bpp[ew * 2 + 0], a1 = bpp[ew * 2 + 1];
        #pragma unroll 4
        for (int j = 0; j < 128; ++j) {
            const float* r = wp + j * 12;   // uniform index -> s_load
            float h = r[9];
            #pragma unroll
            for (int d = 0; d < 9; ++d) h = fmaf(x[d], r[d], h);
            h = fmaxf(h, 0.f);
            a0 = fmaf(h, r[10], a0);
            a1 = fmaf(h, r[11], a1);
        }
        res.x = a0; res.y = a1;
    } else {
        // boundary wave: dense both experts, select per token (old body)
        const bool em = (tid >= n0);
        float a00 = bpp[0], a01 = bpp[1], a10 = bpp[2], a11 = bpp[3];
        #pragma unroll 4
        for (int j = 0; j < 128; ++j) {
            const float* r0 = wpack + j * 12;
            const float* r1 = wpack + 1536 + j * 12;
            float h0 = r0[9], h1 = r1[9];
            #pragma unroll
            for (int d = 0; d < 9; ++d) {
                h0 = fmaf(x[d], r0[d], h0);
                h1 = fmaf(x[d], r1[d], h1);
            }
            h0 = fmaxf(h0, 0.f);
            h1 = fmaxf(h1, 0.f);
            a00 = fmaf(h0, r0[10], a00);
            a01 = fmaf(h0, r0[11], a01);
            a10 = fmaf(h1, r1[10], a10);
            a11 = fmaf(h1, r1[11], a11);
        }
        res.x = em ? a10 : a00;
        res.y = em ? a11 : a01;
    }

    // --- bounce through LDS to restore token order; coalesced fp32 stores ---
    __syncthreads();                        // all xs reads complete
    ((float2*)xs)[t] = res;
    __syncthreads();
    out[blockIdx.x * TPB + tid] = ((float2*)xs)[tid];

    // --- fused finalize: last block computes loss ---
    // gates one-hot value-1.0 -> importance == load == counts.
    // cv^2 ddof=1: var=(c0-c1)^2/2, mean=N/2; loss = 0.01*2*cv^2.
    if (tid == 0) {
        __threadfence();
        unsigned int old = atomicAdd(&cnt_done[1], 1u);
        if (old == NBLK - 1) {
            double c1   = (double)atomicAdd(&cnt_done[0], 0u);  // coherent read
            double c0   = (double)NTOK - c1;
            double diff = c0 - c1;
            double mean = (double)NTOK * 0.5;
            double cv2  = (0.5 * diff * diff) / (mean * mean + 1e-10);
            *loss_out = (float)(0.02 * cv2);
        }
    }
}

extern "C" void kernel_launch(void* const* d_in, const int* in_sizes, int n_in,
                              void* d_out, int out_size, void* d_ws, size_t ws_size,
                              hipStream_t stream) {
    const void* num_prop = d_in[0]; // [N,9] fp32
    // d_in[1] = cat_prop (unused)
    const void* w_gate   = d_in[2]; // [9,2]
    const void* W1       = d_in[3]; // [2,9,128]
    const void* b1       = d_in[4]; // [2,128]
    const void* W2       = d_in[5]; // [2,128,32]
    const void* b2       = d_in[6]; // [2,32]
    const void* Wout     = d_in[7]; // [32,2]
    const void* bout     = d_in[8]; // [2]
    // d_in[9] = k (==1)

    char* ws = (char*)d_ws;
    unsigned int* cnt_done = (unsigned int*)ws;      // @0: [cnt1, done]
    int* flag          = (int*)(ws + 8);             // @8
    float* bpp         = (float*)(ws + 16);          // 4 f
    float* wgf         = (float*)(ws + 64);          // 18 f
    float* wpack       = (float*)(ws + 192);         // 3072 f (expert-major)

    float*  outf = (float*)d_out;                    // FP32: N*2 + loss
    float2* out2 = (float2*)d_out;

    hipLaunchKernelGGL(prep_kernel, dim3(1), dim3(256), 0, stream,
                       num_prop, w_gate, W1, b1, W2, b2, Wout, bout,
                       cnt_done, flag, bpp, wgf, wpack);
    hipLaunchKernelGGL(moe_main, dim3(NBLK), dim3(TPB), 0, stream,
                       num_prop, flag, wgf, bpp, wpack, cnt_done, out2,
                       outf + (size_t)NTOK * 2);
}

// Round 2
// 132.818 us; speedup vs baseline: 1.3104x; 1.3104x over previous
//
#include <hip/hip_runtime.h>

// N=524288, D=9, E=2, H=128, M=32, O=2, K=1.
// LAYOUT (confirmed R6): d_in fp32, d_out FP32 (N*2 outputs + 1 loss).
// NUMERICS: pure fp32 everywhere, no rounding anywhere (prior session).
// R2: expert partition kept (work reduction verified in R1: VALU issue
// 39.5->24.8 us) but with TWO TOKENS PER THREAD so the expert-uniform
// fast path has two independent FMA chains per record (ILP-2, same
// scheduling profile as the proven R0 dense body) and HALF R0's s_load
// rate. Boundary wave (<=1/4) runs the R0 dense-both body for its pair.
// R1's per-block threadfence/done-counter removed (stall source suspect);
// finalize is a separate tiny kernel again.
#define NTOK 524288
#define TPB  256
#define TOKB 512              // tokens per block (2 per thread)
#define NBLK (NTOK / TOKB)    // 1024

__device__ __forceinline__ float bf2f(unsigned short u) {
    union { unsigned int i; float f; } v;
    v.i = ((unsigned int)u) << 16;
    return v.f;
}

// input load: raw fp32 (bf16-buffer fallback kept purely as safety)
__device__ __forceinline__ float ldq(const void* p, int i, bool f32) {
    if (f32) return ((const float*)p)[i];
    return bf2f(((const unsigned short*)p)[i]);
}

// ---------------------------------------------------------------------------
// Prep: detect buffer dtype (safety), zero counter, stage w_gate, fold
// W2@Wout (+ b2@Wout + bout), pack per-hidden-unit weights.
// wpack layout (expert-major): wpack[e*1536 + j*12 + {0..8:W1col, 9:b1,
// 10..11:W2'}] — 48B records, 16B-aligned (j*48 % 16 == 0).
// ---------------------------------------------------------------------------
__global__ void prep_kernel(const void* __restrict__ num_prop,
                            const void* __restrict__ wgate,
                            const void* __restrict__ W1,
                            const void* __restrict__ b1,
                            const void* __restrict__ W2,
                            const void* __restrict__ b2,
                            const void* __restrict__ Wout,
                            const void* __restrict__ bout,
                            unsigned int* __restrict__ cnt1,
                            int* __restrict__ flag,
                            float* __restrict__ bpp,
                            float* __restrict__ wgf,
                            float* __restrict__ wpack)
{
    __shared__ int sflag;
    const int t = threadIdx.x;
    if (t == 0) {
        const unsigned short* u = (const unsigned short*)num_prop;
        int f = 0;
        for (int i = 0; i < 72; ++i) {
            int e = (u[i] >> 7) & 0xFF;
            if (e < 64 || e > 191) f = 1;
        }
        sflag = f; *flag = f; *cnt1 = 0u;
    }
    __syncthreads();
    const bool f32 = (sflag != 0);

    if (t < 18) wgf[t] = ldq(wgate, t, f32);        // w_gate [9,2] raw fp32

    if (t < 4) {  // b''[e][o] = sum_m b2[e][m]*Wout[m][o] + bout[o]
        int e = t >> 1, o = t & 1;
        float acc = ldq(bout, o, f32);
        for (int m = 0; m < 32; ++m)
            acc += ldq(b2, e * 32 + m, f32) * ldq(Wout, m * 2 + o, f32);
        bpp[t] = acc;
    }

    const int e = t >> 7;       // 256 threads -> (e, j)
    const int j = t & 127;
    float p0 = 0.f, p1 = 0.f;
    for (int m = 0; m < 32; ++m) {
        float w = ldq(W2, (e * 128 + j) * 32 + m, f32);
        p0 += w * ldq(Wout, m * 2 + 0, f32);
        p1 += w * ldq(Wout, m * 2 + 1, f32);
    }
    float* dst = wpack + e * 1536 + j * 12;
    #pragma unroll
    for (int d = 0; d < 9; ++d)
        dst[d] = ldq(W1, (e * 9 + d) * 128 + j, f32);
    dst[9]  = ldq(b1, e * 128 + j, f32);
    dst[10] = p0;
    dst[11] = p1;
}

// ---------------------------------------------------------------------------
// Main: 512 tokens/block, 2 per thread. Stage x -> LDS, gate both tokens,
// block-local STABLE partition by expert (ballot + 8-chunk prefix, smap:
// slot -> token). Thread handles slots 2*tid, 2*tid+1 (both in its wave's
// 128-slot range). Waves avoiding the n0 boundary are expert-uniform ->
// single-expert loop: 1 scalar record (12 dwords) feeds 2 independent
// token chains (24 VALU / 48 cyc per j, ILP-2 like R0). Boundary wave
// runs R0's dense-both body for both tokens + per-token select.
// Results bounce through LDS back to token order -> coalesced stores.
// ---------------------------------------------------------------------------
__global__ __launch_bounds__(TPB, 6)
void moe_main(const void* __restrict__ xg,
              const int* __restrict__ flag,
              const float* __restrict__ wgf,
              const float* __restrict__ bpp,
              const float* __restrict__ wpack,
              unsigned int* __restrict__ cnt1,
              float2* __restrict__ out)
{
    __shared__ __align__(16) float xs[TOKB * 9];   // 18432 B
    __shared__ unsigned short smap[TOKB];          // 1024 B
    __shared__ unsigned int wcnt[8];

    const int tid  = threadIdx.x;
    const int lane = tid & 63;
    const int wave = tid >> 6;

    const bool f32 = (*flag) != 0;
    const int gbase = blockIdx.x * (TOKB * 9);
    if (f32) {
        const float* xf = (const float*)xg;
        #pragma unroll
        for (int i = 0; i < 18; ++i)
            xs[tid + i * TPB] = xf[gbase + tid + i * TPB];   // RAW fp32
    } else {
        const unsigned short* xu = (const unsigned short*)xg;
        for (int i = tid; i < TOKB * 9; i += TPB)
            xs[i] = bf2f(xu[gbase + i]);
    }
    __syncthreads();

    // --- gate both tokens (same fmaf chains as accepted kernel) ---
    float l0A = 0.f, l1A = 0.f, l0B = 0.f, l1B = 0.f;
    #pragma unroll
    for (int d = 0; d < 9; ++d) {
        const float wa = wgf[d * 2 + 0], wb = wgf[d * 2 + 1];
        const float xA = xs[tid * 9 + d];
        const float xB = xs[(tid + 256) * 9 + d];
        l0A = fmaf(xA, wa, l0A); l1A = fmaf(xA, wb, l1A);
        l0B = fmaf(xB, wa, l0B); l1B = fmaf(xB, wb, l1B);
    }
    const bool e1A = l1A > l0A;   // tie -> expert 0 (stable top_k)
    const bool e1B = l1B > l0B;

    // --- stable partition over 512 tokens: chunk order = token order ---
    unsigned long long balA = __ballot(e1A);
    unsigned long long balB = __ballot(e1B);
    if (lane == 0) {
        wcnt[wave]     = (unsigned int)__popcll(balA);   // tokens wave*64..
        wcnt[4 + wave] = (unsigned int)__popcll(balB);   // tokens 256+wave*64..
    }
    __syncthreads();
    int pres[8]; int run = 0;
    #pragma unroll
    for (int c = 0; c < 8; ++c) { pres[c] = run; run += (int)wcnt[c]; }
    const int n1 = run;
    const int n0 = TOKB - n1;
    const unsigned long long below = (1ull << lane) - 1ull;
    const int prA = pres[wave]     + (int)__popcll(balA & below);
    const int prB = pres[4 + wave] + (int)__popcll(balB & below);
    const int slotA = e1A ? (n0 + prA) : (tid - prA);
    const int slotB = e1B ? (n0 + prB) : (tid + 256 - prB);
    smap[slotA] = (unsigned short)tid;
    smap[slotB] = (unsigned short)(tid + 256);
    __syncthreads();

    // --- this thread processes slots 2*tid, 2*tid+1 ---
    const int sA = tid * 2, sB = sA + 1;
    const int tA = (int)smap[sA], tB = (int)smap[sB];
    float xa[9], xb[9];
    #pragma unroll
    for (int d = 0; d < 9; ++d) { xa[d] = xs[tA * 9 + d]; xb[d] = xs[tB * 9 + d]; }

    // scalarize uniformity test: wave's slot range = [wave*128, wave*128+128)
    const int wbase = __builtin_amdgcn_readfirstlane(tid & 192) << 1;
    const int n0u   = __builtin_amdgcn_readfirstlane(n0);

    float2 ra, rb;
    if (n0u <= wbase || n0u >= wbase + 128) {
        // expert-uniform wave: one 12-dword record -> two token chains
        const int ew = (n0u <= wbase) ? 1 : 0;
        const float* wp = wpack + ew * 1536;
        float a0 = bpp[ew * 2 + 0], a1 = bpp[ew * 2 + 1];
        float c0 = a0, c1 = a1;
        #pragma unroll 4
        for (int j = 0; j < 128; ++j) {
            const float* r = wp + j * 12;   // uniform index -> s_load
            float hA = r[9], hB = r[9];
            #pragma unroll
            for (int d = 0; d < 9; ++d) {
                hA = fmaf(xa[d], r[d], hA);
                hB = fmaf(xb[d], r[d], hB);
            }
            hA = fmaxf(hA, 0.f); hB = fmaxf(hB, 0.f);
            a0 = fmaf(hA, r[10], a0); a1 = fmaf(hA, r[11], a1);
            c0 = fmaf(hB, r[10], c0); c1 = fmaf(hB, r[11], c1);
        }
        ra.x = a0; ra.y = a1; rb.x = c0; rb.y = c1;
    } else {
        // boundary wave (<=1/block): dense both experts, select per token
        const bool eA = (sA >= n0u), eB = (sB >= n0u);
        float aA0 = bpp[0], aA1 = bpp[1], aA2 = bpp[2], aA3 = bpp[3];
        float aB0 = bpp[0], aB1 = bpp[1], aB2 = bpp[2], aB3 = bpp[3];
        #pragma unroll 2
        for (int j = 0; j < 128; ++j) {
            const float* r0 = wpack + j * 12;
            const float* r1 = wpack + 1536 + j * 12;
            float hA0 = r0[9], hA1 = r1[9], hB0 = r0[9], hB1 = r1[9];
            #pragma unroll
            for (int d = 0; d < 9; ++d) {
                hA0 = fmaf(xa[d], r0[d], hA0);
                hA1 = fmaf(xa[d], r1[d], hA1);
                hB0 = fmaf(xb[d], r0[d], hB0);
                hB1 = fmaf(xb[d], r1[d], hB1);
            }
            hA0 = fmaxf(hA0, 0.f); hA1 = fmaxf(hA1, 0.f);
            hB0 = fmaxf(hB0, 0.f); hB1 = fmaxf(hB1, 0.f);
            aA0 = fmaf(hA0, r0[10], aA0); aA1 = fmaf(hA0, r0[11], aA1);
            aA2 = fmaf(hA1, r1[10], aA2); aA3 = fmaf(hA1, r1[11], aA3);
            aB0 = fmaf(hB0, r0[10], aB0); aB1 = fmaf(hB0, r0[11], aB1);
            aB2 = fmaf(hB1, r1[10], aB2); aB3 = fmaf(hB1, r1[11], aB3);
        }
        ra.x = eA ? aA2 : aA0; ra.y = eA ? aA3 : aA1;
        rb.x = eB ? aB2 : aB0; rb.y = eB ? aB3 : aB1;
    }

    // --- bounce through LDS to token order; coalesced float2 stores ---
    __syncthreads();                        // all xs reads complete
    float2* ob = (float2*)xs;
    ob[tA] = ra;
    ob[tB] = rb;
    __syncthreads();
    const int obase = blockIdx.x * TOKB;
    out[obase + tid]       = ob[tid];
    out[obase + 256 + tid] = ob[256 + tid];
    if (tid == 0) atomicAdd(cnt1, (unsigned int)n1);
}

// Loss: gates one-hot value-1.0 -> importance == load == counts.
// cv^2 ddof=1: var=(c0-c1)^2/2, mean=N/2; loss = 0.01*2*cv^2 (~1e-9).
__global__ void finalize_kernel(const unsigned int* __restrict__ cnt1,
                                float* __restrict__ loss_out)
{
    double c1 = (double)(*cnt1);
    double c0 = (double)NTOK - c1;
    double diff = c0 - c1;
    double mean = (double)NTOK * 0.5;
    double var  = 0.5 * diff * diff;
    double cv2  = var / (mean * mean + 1e-10);
    *loss_out = (float)(0.02 * cv2);
}

extern "C" void kernel_launch(void* const* d_in, const int* in_sizes, int n_in,
                              void* d_out, int out_size, void* d_ws, size_t ws_size,
                              hipStream_t stream) {
    const void* num_prop = d_in[0]; // [N,9] fp32
    // d_in[1] = cat_prop (unused)
    const void* w_gate   = d_in[2]; // [9,2]
    const void* W1       = d_in[3]; // [2,9,128]
    const void* b1       = d_in[4]; // [2,128]
    const void* W2       = d_in[5]; // [2,128,32]
    const void* b2       = d_in[6]; // [2,32]
    const void* Wout     = d_in[7]; // [32,2]
    const void* bout     = d_in[8]; // [2]
    // d_in[9] = k (==1)

    char* ws = (char*)d_ws;
    unsigned int* cnt1 = (unsigned int*)ws;          // @0
    int* flag          = (int*)(ws + 8);             // @8
    float* bpp         = (float*)(ws + 16);          // 4 f
    float* wgf         = (float*)(ws + 64);          // 18 f
    float* wpack       = (float*)(ws + 192);         // 3072 f (expert-major)

    float*  outf = (float*)d_out;                    // FP32: N*2 + loss
    float2* out2 = (float2*)d_out;

    hipLaunchKernelGGL(prep_kernel, dim3(1), dim3(256), 0, stream,
                       num_prop, w_gate, W1, b1, W2, b2, Wout, bout,
                       cnt1, flag, bpp, wgf, wpack);
    hipLaunchKernelGGL(moe_main, dim3(NBLK), dim3(TPB), 0, stream,
                       num_prop, flag, wgf, bpp, wpack, cnt1, out2);
    hipLaunchKernelGGL(finalize_kernel, dim3(1), dim3(1), 0, stream,
                       cnt1, outf + (size_t)NTOK * 2);
}